// Round 2
// baseline (672.739 us; speedup 1.0000x reference)
//
#include <hip/hip_runtime.h>

#define NBINS 15

// DPP move helper: returns v permuted by CTRL; lanes not written by the pattern
// keep their own value (old = v, bound_ctrl = false).
template <int CTRL>
__device__ __forceinline__ float dpp_mov_f(float v) {
    return __int_as_float(__builtin_amdgcn_update_dpp(
        __float_as_int(v), __float_as_int(v), CTRL, 0xF, 0xF, false));
}

// 5-stage per-32-lane reductions on the VALU (no LDS pipe). Result valid in
// lanes 16-31 (half A) and 48-63 (half B); broadcast via readlane(31/63).
__device__ __forceinline__ float half_reduce_max(float v) {
    v = fmaxf(v, dpp_mov_f<0xB1>(v));    // quad_perm xor1
    v = fmaxf(v, dpp_mov_f<0x4E>(v));    // quad_perm xor2
    v = fmaxf(v, dpp_mov_f<0x141>(v));   // row_half_mirror
    v = fmaxf(v, dpp_mov_f<0x140>(v));   // row_mirror
    v = fmaxf(v, dpp_mov_f<0x142>(v));   // row_bcast15
    return v;
}
__device__ __forceinline__ float half_reduce_sum(float v) {
    v += dpp_mov_f<0xB1>(v);
    v += dpp_mov_f<0x4E>(v);
    v += dpp_mov_f<0x141>(v);
    v += dpp_mov_f<0x140>(v);
    v += dpp_mov_f<0x142>(v);
    return v;
}

// Full per-row pipeline. All lanes end up with the (per-half-uniform) bin/acc/fc
// and accumulate into per-thread register histograms (lane k<15 owns bin k of its
// half). No LDS traffic here at all.
__device__ __forceinline__ void process_row(
    const float4 v, const int lab, const int lane32, const int half,
    unsigned int& cnt_r, unsigned int& acc_r, unsigned long long& conf_r)
{
    // ---- max ----
    float m4 = fmaxf(fmaxf(v.x, v.y), fmaxf(v.z, v.w));
    float Mr = half_reduce_max(m4);
    const float MA = __int_as_float(__builtin_amdgcn_readlane(__float_as_int(Mr), 31));
    const float MB = __int_as_float(__builtin_amdgcn_readlane(__float_as_int(Mr), 63));
    const float Mh = half ? MB : MA;

    // ---- sum of exp(x - max) ----
    float e = __expf(v.x - Mh) + __expf(v.y - Mh) + __expf(v.z - Mh) + __expf(v.w - Mh);
    float Sr = half_reduce_sum(e);
    const int SAi = __builtin_amdgcn_readlane(__float_as_int(Sr), 31);
    const int SBi = __builtin_amdgcn_readlane(__float_as_int(Sr), 63);
    const float Sh = __int_as_float(half ? SBi : SAi);

    // ---- argmax, first occurrence (lane i covers contiguous idx 4i..4i+3) ----
    int idx_local = (v.x == Mh) ? 0 : (v.y == Mh) ? 1 : (v.z == Mh) ? 2 : 3;
    unsigned long long bal = __ballot(m4 == Mh);
    unsigned lo = (unsigned)bal;
    unsigned hi = (unsigned)(bal >> 32);
    int winA = __ffs(lo) - 1;
    int winB = __ffs(hi) - 1;
    int predA = (winA << 2) + __builtin_amdgcn_readlane(idx_local, winA);
    int predB = (winB << 2) + __builtin_amdgcn_readlane(idx_local, winB + 32);
    const int pred = half ? predB : predA;

    // ---- bin / acc / fixed-point conf (uniform per half, computed on all lanes) ----
    float conf = 1.0f / Sh;
    int bin = (int)ceilf(conf * 15.0f) - 1;       // searchsorted(uppers, conf, 'left')
    bin = max(0, min(NBINS - 1, bin));
    unsigned int acc = (pred == lab) ? 1u : 0u;
    // exact floor(conf * 2^32) via mantissa shift (== (u64)((double)conf*2^32))
    unsigned int cb = __float_as_uint(conf);
    unsigned int mant = (cb & 0x7fffffu) | 0x800000u;
    int sh = (int)(cb >> 23) - 118;               // exp-127 + 32 - 23
    unsigned long long fc = (sh >= 0)
        ? ((unsigned long long)mant << sh)
        : ((unsigned long long)mant >> (-sh));

    // ---- register-histogram accumulate: lane k (<15) owns bin k of its half ----
    const bool own = (lane32 < NBINS) && (bin == lane32);
    cnt_r  += own ? 1u : 0u;
    acc_r  += own ? acc : 0u;
    conf_r += own ? fc : 0ULL;
}

// Pass 1: half-wave (32 lanes) per row, 4 rows per iteration (4 independent
// dwordx4 loads + one int4 label load -> 4x memory-level parallelism).
// Per-block 15-bin partials: count (u32), correct (u32), conf fp*2^32 (u64).
__global__ __launch_bounds__(256, 8) void mce_pass1(
    const float* __restrict__ logits, const int* __restrict__ labels,
    unsigned long long* __restrict__ conf_part,
    unsigned int* __restrict__ cnt_part,
    unsigned int* __restrict__ acc_part,
    int n)
{
    __shared__ unsigned int s_cnt[NBINS];
    __shared__ unsigned int s_acc[NBINS];
    __shared__ unsigned long long s_conf[NBINS];
    if (threadIdx.x < NBINS) {
        s_cnt[threadIdx.x] = 0u;
        s_acc[threadIdx.x] = 0u;
        s_conf[threadIdx.x] = 0ULL;
    }
    __syncthreads();

    const int lane32 = threadIdx.x & 31;
    const int half   = (threadIdx.x >> 5) & 1;
    const int hw_global = blockIdx.x * 8 + (threadIdx.x >> 5);
    const int hw_total  = gridDim.x * 8;
    const int B = gridDim.x;

    unsigned int cnt_r = 0u, acc_r = 0u;
    unsigned long long conf_r = 0ULL;

    const int stride = hw_total * 4;          // 4 rows per half-wave per iter
    int r0 = hw_global * 4;
    for (; r0 + 4 <= n; r0 += stride) {
        const float* base = logits + (size_t)r0 * 128 + lane32 * 4;
        const float4 v0 = *(const float4*)(base);
        const float4 v1 = *(const float4*)(base + 128);
        const float4 v2 = *(const float4*)(base + 256);
        const float4 v3 = *(const float4*)(base + 384);
        const int4 lab4 = *(const int4*)(labels + r0);   // r0 % 4 == 0 -> 16B aligned
        process_row(v0, lab4.x, lane32, half, cnt_r, acc_r, conf_r);
        process_row(v1, lab4.y, lane32, half, cnt_r, acc_r, conf_r);
        process_row(v2, lab4.z, lane32, half, cnt_r, acc_r, conf_r);
        process_row(v3, lab4.w, lane32, half, cnt_r, acc_r, conf_r);
    }
    for (; r0 < n; ++r0) {                    // tail (<4 rows, only some half-waves)
        const float4 v = *(const float4*)(logits + (size_t)r0 * 128 + lane32 * 4);
        process_row(v, labels[r0], lane32, half, cnt_r, acc_r, conf_r);
    }

    // one-shot merge of register histograms (lanes 0-14 and 32-46 of each wave)
    if (lane32 < NBINS) {
        atomicAdd(&s_cnt[lane32], cnt_r);
        atomicAdd(&s_acc[lane32], acc_r);
        atomicAdd(&s_conf[lane32], conf_r);
    }
    __syncthreads();
    // transposed partials [bin][block] so pass2 reads are coalesced
    if (threadIdx.x < NBINS) {
        cnt_part[threadIdx.x * B + blockIdx.x]  = s_cnt[threadIdx.x];
        acc_part[threadIdx.x * B + blockIdx.x]  = s_acc[threadIdx.x];
        conf_part[(size_t)threadIdx.x * B + blockIdx.x] = s_conf[threadIdx.x];
    }
}

// Pass 2: one block, 15 waves; wave w reduces bin w across all B block-partials
// (coalesced: consecutive lanes read consecutive blocks). Integer sums ->
// fully deterministic; then compute avgs/gap/mce and write 31 floats.
__global__ __launch_bounds__(960) void mce_pass2(
    const unsigned long long* __restrict__ conf_part,
    const unsigned int* __restrict__ cnt_part,
    const unsigned int* __restrict__ acc_part,
    int B, float* __restrict__ out)
{
    __shared__ float s_prob[NBINS], s_accu[NBINS], s_gap[NBINS];
    __shared__ int s_ne[NBINS];

    const int bin  = threadIdx.x >> 6;   // 0..14
    const int lane = threadIdx.x & 63;

    unsigned long long csum = 0ULL;
    unsigned int cn = 0u, ac = 0u;
    #pragma unroll 4
    for (int i = lane; i < B; i += 64) {
        csum += conf_part[(size_t)bin * B + i];
        cn   += cnt_part[bin * B + i];
        ac   += acc_part[bin * B + i];
    }
    #pragma unroll
    for (int off = 32; off >= 1; off >>= 1) {
        csum += __shfl_xor(csum, off, 64);
        cn   += __shfl_xor(cn, off, 64);
        ac   += __shfl_xor(ac, off, 64);
    }

    if (lane == 0) {
        if (cn > 0u) {
            float p = (float)(((double)csum * (1.0 / 4294967296.0)) / (double)cn);
            float a = (float)((double)ac / (double)cn);
            s_prob[bin] = p;
            s_accu[bin] = a;
            s_gap[bin]  = fabsf(p - a);
            s_ne[bin]   = 1;
        } else {
            s_prob[bin] = 0.0f;
            s_accu[bin] = 0.0f;
            s_gap[bin]  = 0.0f;
            s_ne[bin]   = 0;
        }
    }
    __syncthreads();

    if (threadIdx.x == 0) {
        float mce = -1e30f;
        for (int b = 0; b < NBINS; ++b)
            if (s_ne[b] && s_gap[b] > mce) mce = s_gap[b];
        out[0] = mce;
    }
    if (threadIdx.x < NBINS) {
        out[1 + threadIdx.x]  = s_prob[threadIdx.x];
        out[16 + threadIdx.x] = s_accu[threadIdx.x];
    }
}

extern "C" void kernel_launch(void* const* d_in, const int* in_sizes, int n_in,
                              void* d_out, int out_size, void* d_ws, size_t ws_size,
                              hipStream_t stream) {
    const float* logits = (const float*)d_in[0];
    const int*   labels = (const int*)d_in[1];
    const int n = in_sizes[1];              // 1e6 rows; C fixed at 128

    int B = 2048;                           // 2048 blocks * 4 waves = 8192 waves = 32/CU
    const size_t per_block = (size_t)NBINS * (8 + 4 + 4);
    if ((size_t)B * per_block > ws_size) B = (int)(ws_size / per_block);
    if (B < 1) B = 1;

    unsigned long long* conf_part = (unsigned long long*)d_ws;
    unsigned int* cnt_part = (unsigned int*)((char*)d_ws + (size_t)B * NBINS * 8);
    unsigned int* acc_part = (unsigned int*)((char*)d_ws + (size_t)B * NBINS * 12);

    mce_pass1<<<B, 256, 0, stream>>>(logits, labels, conf_part, cnt_part, acc_part, n);
    mce_pass2<<<1, 960, 0, stream>>>(conf_part, cnt_part, acc_part, B, (float*)d_out);
}